// Round 10
// baseline (121.627 us; speedup 1.0000x reference)
//
#include <hip/hip_runtime.h>

#define NTOK 256
#define LOG2E 1.44269504088896340736f
#define LN_EPS 1e-5f

typedef float v2f __attribute__((ext_vector_type(2)));

static __device__ __forceinline__ v2f splat2(float s) { v2f r; r.x = s; r.y = s; return r; }

// quad-perm DPP shuffle (VALU pipe): xor1 = 0xB1, xor2 = 0x4E
template <int CTRL>
static __device__ __forceinline__ float dppq(float v) {
    return __int_as_float(
        __builtin_amdgcn_update_dpp(0, __float_as_int(v), CTRL, 0xF, 0xF, true));
}
static __device__ __forceinline__ v2f quad_sum2(v2f v) {
    v2f t;
    t.x = dppq<0xB1>(v.x); t.y = dppq<0xB1>(v.y);
    v += t;
    t.x = dppq<0x4E>(v.x); t.y = dppq<0x4E>(v.y);
    return v + t;
}

// Rank-reduced decoder layer (math identical to passing R9), reshaped:
// grid 2048 x 256 thr -> 2048 thr/CU (8 waves/SIMD). Block = half row
// (128 queries); lane = (qp 0..63, kq 0..3); v2f packs queries {qa, qa+64}.
// SA keys: scalar n per key, read 4-at-a-time via ds_read_b128 from padded
// n_sa[4][68] (kq bases 272 B apart -> banks 0/4/8/12, conflict-free).
// CA keys: float2 m per key, 2-at-a-time b128 from mca[4][68].
// Quad-DPP split-k combine; ONE barrier.
__global__ __launch_bounds__(256, 8)
void att_decoder_kernel(
    const float* __restrict__ x, const float* __restrict__ m,
    const float* __restrict__ sa_w_in, const float* __restrict__ sa_b_in,
    const float* __restrict__ sa_w_out, const float* __restrict__ sa_b_out,
    const float* __restrict__ ca_w_in, const float* __restrict__ ca_b_in,
    const float* __restrict__ ca_w_out, const float* __restrict__ ca_b_out,
    const float* __restrict__ ln1_g, const float* __restrict__ ln1_b,
    const float* __restrict__ ln2_g, const float* __restrict__ ln2_b,
    const float* __restrict__ ln3_g, const float* __restrict__ ln3_b,
    const float* __restrict__ f_w1, const float* __restrict__ f_b1,
    const float* __restrict__ f_ln_g, const float* __restrict__ f_ln_b,
    const float* __restrict__ f_w2, const float* __restrict__ f_b2,
    float* __restrict__ out)
{
    const int tid  = threadIdx.x;
    const int row  = blockIdx.x >> 1;
    const int half = blockIdx.x & 1;
    const int qp   = tid >> 2;            // 0..63
    const int kq   = tid & 3;             // key quarter

    __shared__ alignas(16) float  n_sa[4][68];   // LN1 scalar per key, padded
    __shared__ alignas(16) float2 mca [4][68];   // raw m per key, padded

    const float2* __restrict__ x2 = (const float2*)x;
    const float2* __restrict__ m2 = (const float2*)m;

    const float g0 = ln1_g[0], b0 = ln1_b[0], g1 = ln1_g[1], b1 = ln1_b[1];

    // ---- staging: thread tid stages key j = tid ----
    {
        float2 xv = x2[row * NTOK + tid];
        float d = 0.5f * (xv.x - xv.y);
        n_sa[tid >> 6][tid & 63] = d * rsqrtf(d * d + LN_EPS);
        mca [tid >> 6][tid & 63] = m2[row * NTOK + tid];
    }

    // ---- own 2 queries {qa, qa+64}: LN1 scalar -> h0,h1 (v2f) ----
    const int qa = half * 128 + qp;
    v2f nq;
    {
        float2 q0 = x2[row * NTOK + qa];
        float2 q1 = x2[row * NTOK + qa + 64];
        float d0 = 0.5f * (q0.x - q0.y);
        nq.x = d0 * rsqrtf(d0 * d0 + LN_EPS);
        float d1 = 0.5f * (q1.x - q1.y);
        nq.y = d1 * rsqrtf(d1 * d1 + LN_EPS);
    }
    v2f h0 = nq * splat2(g0) + splat2(b0);
    v2f h1 = nq * splat2(-g1) + splat2(b1);

    __syncthreads();   // the only barrier

    const float sc = 0.7071067811865476f * LOG2E;

    // ---- self-attention (rank-1 in LN1 scalar n) ----
    {
        const float ak0 = g0*sa_w_in[4]  - g1*sa_w_in[5];
        const float ak1 = g0*sa_w_in[6]  - g1*sa_w_in[7];
        const float av0 = g0*sa_w_in[8]  - g1*sa_w_in[9];
        const float bv0 = b0*sa_w_in[8]  + b1*sa_w_in[9]  + sa_b_in[4];
        const float av1 = g0*sa_w_in[10] - g1*sa_w_in[11];
        const float bv1 = b0*sa_w_in[10] + b1*sa_w_in[11] + sa_b_in[5];
        v2f qh0 = h0*splat2(sa_w_in[0]) + h1*splat2(sa_w_in[1]) + splat2(sa_b_in[0]);
        v2f qh1 = h0*splat2(sa_w_in[2]) + h1*splat2(sa_w_in[3]) + splat2(sa_b_in[1]);
        v2f A = (qh0*splat2(ak0) + qh1*splat2(ak1)) * splat2(sc);
        v2f S0 = splat2(0.f), S1 = splat2(0.f);
        const float4* __restrict__ np = (const float4*)n_sa[kq];
        #pragma unroll 4
        for (int i = 0; i < 16; ++i) {
            float4 n4 = np[i];                     // 4 keys per ds_read_b128
#define SA_KEY(NC) {                                                        \
            v2f s = A * splat2(NC);                                         \
            v2f p; p.x = __builtin_amdgcn_exp2f(s.x);                       \
                   p.y = __builtin_amdgcn_exp2f(s.y);                       \
            S0 += p; S1 += p * splat2(NC); }
            SA_KEY(n4.x) SA_KEY(n4.y) SA_KEY(n4.z) SA_KEY(n4.w)
#undef SA_KEY
        }
        S0 = quad_sum2(S0); S1 = quad_sum2(S1);
        v2f R;
        R.x = S1.x * __builtin_amdgcn_rcpf(S0.x);
        R.y = S1.y * __builtin_amdgcn_rcpf(S0.y);
        v2f a0 = splat2(av0)*R + splat2(bv0);
        v2f a1 = splat2(av1)*R + splat2(bv1);
        h0 += a0*splat2(sa_w_out[0]) + a1*splat2(sa_w_out[1]) + splat2(sa_b_out[0]);
        h1 += a0*splat2(sa_w_out[2]) + a1*splat2(sa_w_out[3]) + splat2(sa_b_out[1]);
    }

    // ---- LN2 (per component) ----
    {
        const float G0 = ln2_g[0], B0 = ln2_b[0], G1 = ln2_g[1], B1 = ln2_b[1];
        float d0 = 0.5f * (h0.x - h1.x);
        float n0 = d0 * rsqrtf(d0 * d0 + LN_EPS);
        float d1 = 0.5f * (h0.y - h1.y);
        float n1 = d1 * rsqrtf(d1 * d1 + LN_EPS);
        h0.x = n0*G0 + B0;  h0.y = n1*G0 + B0;
        h1.x = -n0*G1 + B1; h1.y = -n1*G1 + B1;
    }

    // ---- cross-attention (rank-2 in m, const dropped) ----
    v2f T0, T1, T2;
    {
        v2f qh0 = h0*splat2(ca_w_in[0]) + h1*splat2(ca_w_in[1]) + splat2(ca_b_in[0]);
        v2f qh1 = h0*splat2(ca_w_in[2]) + h1*splat2(ca_w_in[3]) + splat2(ca_b_in[1]);
        v2f C0 = (qh0*splat2(ca_w_in[4]) + qh1*splat2(ca_w_in[6])) * splat2(sc);
        v2f C1 = (qh0*splat2(ca_w_in[5]) + qh1*splat2(ca_w_in[7])) * splat2(sc);
        T0 = splat2(0.f); T1 = splat2(0.f); T2 = splat2(0.f);
        const float4* __restrict__ mp = (const float4*)mca[kq];
        #pragma unroll 4
        for (int i = 0; i < 32; ++i) {
            float4 m4 = mp[i];                     // 2 keys per ds_read_b128
#define CA_KEY(M0, M1) {                                                    \
            v2f s = C0*splat2(M0) + C1*splat2(M1);                          \
            v2f p; p.x = __builtin_amdgcn_exp2f(s.x);                       \
                   p.y = __builtin_amdgcn_exp2f(s.y);                       \
            T0 += p; T1 += p*splat2(M0); T2 += p*splat2(M1); }
            CA_KEY(m4.x, m4.y) CA_KEY(m4.z, m4.w)
#undef CA_KEY
        }
        T0 = quad_sum2(T0); T1 = quad_sum2(T1); T2 = quad_sum2(T2);
    }

    // ---- scalar epilogue: component c = kq&1; lanes kq<2 store ----
    const int c = kq & 1;
    float t0 = c ? T0.y : T0.x;
    float t1 = c ? T1.y : T1.x;
    float t2 = c ? T2.y : T2.x;
    float s0 = c ? h0.y : h0.x;
    float s1 = c ? h1.y : h1.x;
    float rT = __builtin_amdgcn_rcpf(t0);
    float U1 = t1 * rT, U2 = t2 * rT;
    float A0 = ca_w_in[8]*U1  + ca_w_in[9]*U2  + ca_b_in[4];
    float A1 = ca_w_in[10]*U1 + ca_w_in[11]*U2 + ca_b_in[5];
    s0 += A0*ca_w_out[0] + A1*ca_w_out[1] + ca_b_out[0];
    s1 += A0*ca_w_out[2] + A1*ca_w_out[3] + ca_b_out[1];

    // ---- LN3 ----
    {
        float d = 0.5f * (s0 - s1);
        float n = d * rsqrtf(d * d + LN_EPS);
        s0 =  n*ln3_g[0] + ln3_b[0];
        s1 = -n*ln3_g[1] + ln3_b[1];
    }

    // ---- FFN: Linear(2,10) -> LN(10) -> ReLU -> Linear(10,2), residual ----
    {
        float ff[10];
        #pragma unroll
        for (int i = 0; i < 10; ++i)
            ff[i] = s0*f_w1[2*i] + s1*f_w1[2*i+1] + f_b1[i];
        float mu = 0.f;
        #pragma unroll
        for (int i = 0; i < 10; ++i) mu += ff[i];
        mu *= 0.1f;
        float var = 0.f;
        #pragma unroll
        for (int i = 0; i < 10; ++i) { float d = ff[i] - mu; var += d * d; }
        var *= 0.1f;
        float r = rsqrtf(var + LN_EPS);
        float o0 = 0.f, o1 = 0.f;
        #pragma unroll
        for (int i = 0; i < 10; ++i) {
            float n = (ff[i] - mu) * r * f_ln_g[i] + f_ln_b[i];
            n = fmaxf(n, 0.f);
            o0 += n * f_w2[i];               // f_w2 is [2,10] row-major
            o1 += n * f_w2[10 + i];
        }
        s0 += o0 + f_b2[0];
        s1 += o1 + f_b2[1];
    }

    if (kq < 2)
        ((float2*)out)[row * NTOK + qa + (c << 6)] = make_float2(s0, s1);
}

extern "C" void kernel_launch(void* const* d_in, const int* in_sizes, int n_in,
                              void* d_out, int out_size, void* d_ws, size_t ws_size,
                              hipStream_t stream) {
    const float* x        = (const float*)d_in[0];
    const float* m        = (const float*)d_in[1];
    const float* sa_w_in  = (const float*)d_in[2];
    const float* sa_b_in  = (const float*)d_in[3];
    const float* sa_w_out = (const float*)d_in[4];
    const float* sa_b_out = (const float*)d_in[5];
    const float* ca_w_in  = (const float*)d_in[6];
    const float* ca_b_in  = (const float*)d_in[7];
    const float* ca_w_out = (const float*)d_in[8];
    const float* ca_b_out = (const float*)d_in[9];
    const float* ln1_g    = (const float*)d_in[10];
    const float* ln1_b    = (const float*)d_in[11];
    const float* ln2_g    = (const float*)d_in[12];
    const float* ln2_b    = (const float*)d_in[13];
    const float* ln3_g    = (const float*)d_in[14];
    const float* ln3_b    = (const float*)d_in[15];
    const float* f_w1     = (const float*)d_in[16];
    const float* f_b1     = (const float*)d_in[17];
    const float* f_ln_g   = (const float*)d_in[18];
    const float* f_ln_b   = (const float*)d_in[19];
    const float* f_w2     = (const float*)d_in[20];
    const float* f_b2     = (const float*)d_in[21];

    const int nbatch = in_sizes[0] / (NTOK * 2);   // 1024
    att_decoder_kernel<<<nbatch * 2, 256, 0, stream>>>(
        x, m, sa_w_in, sa_b_in, sa_w_out, sa_b_out,
        ca_w_in, ca_b_in, ca_w_out, ca_b_out,
        ln1_g, ln1_b, ln2_g, ln2_b, ln3_g, ln3_b,
        f_w1, f_b1, f_ln_g, f_ln_b, f_w2, f_b2,
        (float*)d_out);
}

// Round 11
// 109.226 us; speedup vs baseline: 1.1135x; 1.1135x over previous
//
#include <hip/hip_runtime.h>
#include <math.h>

#define NTOK 256
#define LOG2E 1.44269504088896340736f
#define LN_EPS 1e-5f
#define PI_F 3.14159265358979323846f

// quad-perm DPP (VALU pipe): xor1 = 0xB1, xor2 = 0x4E
template <int CTRL>
static __device__ __forceinline__ float dppq(float v) {
    return __int_as_float(
        __builtin_amdgcn_update_dpp(0, __float_as_int(v), CTRL, 0xF, 0xF, true));
}
static __device__ __forceinline__ float qsum(float v) {
    v += dppq<0xB1>(v);
    v += dppq<0x4E>(v);
    return v;
}

// Clenshaw for 32 Chebyshev coefficients (c[0] + sum c[i] T_i(x)).
static __device__ __forceinline__ float clenshaw32(const float* c, float x) {
    const float4* c4 = (const float4*)c;
    float x2 = x + x;
    float b1 = 0.f, b2 = 0.f, b;
#define STEPC(cv) b = fmaf(x2, b1, cv) - b2; b2 = b1; b1 = b;
    float4 q;
    q = c4[7]; STEPC(q.w) STEPC(q.z) STEPC(q.y) STEPC(q.x)
    q = c4[6]; STEPC(q.w) STEPC(q.z) STEPC(q.y) STEPC(q.x)
    q = c4[5]; STEPC(q.w) STEPC(q.z) STEPC(q.y) STEPC(q.x)
    q = c4[4]; STEPC(q.w) STEPC(q.z) STEPC(q.y) STEPC(q.x)
    q = c4[3]; STEPC(q.w) STEPC(q.z) STEPC(q.y) STEPC(q.x)
    q = c4[2]; STEPC(q.w) STEPC(q.z) STEPC(q.y) STEPC(q.x)
    q = c4[1]; STEPC(q.w) STEPC(q.z) STEPC(q.y) STEPC(q.x)
    q = c4[0]; STEPC(q.w) STEPC(q.z) STEPC(q.y)
#undef STEPC
    return fmaf(x, b1, q.x) - b2;
}

// Per row: the whole layer is a 1-D function chain of per-token scalars.
// SA: score = A(nq)*n_k, A linear in nq; result R(nq) = tilted mean of n_k.
// CA: (C0,C1) linear in n2; results U1(n2), U2(n2) = tilted means of m.
// Build P=32 Chebyshev tables of R,U1,U2 per row (64 node-jobs x quad
// split-k), DCT -> coefficients, then each query: exact algebra + 3
// Clenshaw evals. Exps: 32/thread (was 256). LN2's sharp n->n2 map is
// evaluated EXACTLY per query; only smooth sums are interpolated.
__global__ __launch_bounds__(256, 4)
void att_decoder_kernel(
    const float* __restrict__ x, const float* __restrict__ m,
    const float* __restrict__ sa_w_in, const float* __restrict__ sa_b_in,
    const float* __restrict__ sa_w_out, const float* __restrict__ sa_b_out,
    const float* __restrict__ ca_w_in, const float* __restrict__ ca_b_in,
    const float* __restrict__ ca_w_out, const float* __restrict__ ca_b_out,
    const float* __restrict__ ln1_g, const float* __restrict__ ln1_b,
    const float* __restrict__ ln2_g, const float* __restrict__ ln2_b,
    const float* __restrict__ ln3_g, const float* __restrict__ ln3_b,
    const float* __restrict__ f_w1, const float* __restrict__ f_b1,
    const float* __restrict__ f_ln_g, const float* __restrict__ f_ln_b,
    const float* __restrict__ f_w2, const float* __restrict__ f_b2,
    float* __restrict__ out)
{
    const int tid = threadIdx.x;
    const int row = blockIdx.x;

    __shared__ alignas(16) float  n_sa[4][68];   // LN1 scalar per key (padded)
    __shared__ alignas(16) float2 mca [4][68];   // raw m per key (padded)
    __shared__ float tab[3][32];                 // R / U1 / U2 node values
    __shared__ alignas(16) float ctab[3][32];    // Chebyshev coefficients

    // ---- stage keys + own-query LN1 scalar ----
    float2 xv = ((const float2*)x)[row * NTOK + tid];
    float dq = 0.5f * (xv.x - xv.y);
    float nq = dq * rsqrtf(dq * dq + LN_EPS);
    n_sa[tid >> 6][tid & 63] = nq;
    mca [tid >> 6][tid & 63] = ((const float2*)m)[row * NTOK + tid];

    // ---- block-uniform linearization constants (scalar/SGPR) ----
    const float g0 = ln1_g[0], b0 = ln1_b[0], g1 = ln1_g[1], b1 = ln1_b[1];
    const float scl = 0.7071067811865476f * LOG2E;
    // SA: key/value linear in n; query exponent A(n) = Asc*n + Aoff
    const float ak0 = g0*sa_w_in[4]  - g1*sa_w_in[5];
    const float ak1 = g0*sa_w_in[6]  - g1*sa_w_in[7];
    const float av0 = g0*sa_w_in[8]  - g1*sa_w_in[9];
    const float bv0 = b0*sa_w_in[8]  + b1*sa_w_in[9]  + sa_b_in[4];
    const float av1 = g0*sa_w_in[10] - g1*sa_w_in[11];
    const float bv1 = b0*sa_w_in[10] + b1*sa_w_in[11] + sa_b_in[5];
    const float kq0 = sa_w_in[0]*g0 - sa_w_in[1]*g1;
    const float kb0 = sa_w_in[0]*b0 + sa_w_in[1]*b1 + sa_b_in[0];
    const float kq1 = sa_w_in[2]*g0 - sa_w_in[3]*g1;
    const float kb1 = sa_w_in[2]*b0 + sa_w_in[3]*b1 + sa_b_in[1];
    const float Asc  = scl * (kq0*ak0 + kq1*ak1);
    const float Aoff = scl * (kb0*ak0 + kb1*ak1);
    // CA: C0(n2), C1(n2) linear in n2
    const float G0 = ln2_g[0], B0 = ln2_b[0], G1 = ln2_g[1], B1 = ln2_b[1];
    const float e0a = ca_w_in[0]*G0 - ca_w_in[1]*G1;
    const float e0b = ca_w_in[0]*B0 + ca_w_in[1]*B1 + ca_b_in[0];
    const float e1a = ca_w_in[2]*G0 - ca_w_in[3]*G1;
    const float e1b = ca_w_in[2]*B0 + ca_w_in[3]*B1 + ca_b_in[1];
    const float c0a = scl * (e0a*ca_w_in[4] + e1a*ca_w_in[6]);
    const float c0b = scl * (e0b*ca_w_in[4] + e1b*ca_w_in[6]);
    const float c1a = scl * (e0a*ca_w_in[5] + e1a*ca_w_in[7]);
    const float c1b = scl * (e0b*ca_w_in[5] + e1b*ca_w_in[7]);

    __syncthreads();   // keys staged

    // ---- table phase: 64 node-jobs (32 SA + 32 CA) x 4-way split-k ----
    {
        const int nj = tid >> 2, kq = tid & 3;
        const int jj = nj & 31;
        const float xnode = cosf((float)(2*jj + 1) * (PI_F / 64.f));
        if (nj < 32) {
            const float A = Asc * xnode + Aoff;
            const float4* np4 = (const float4*)n_sa[kq];
            float S0 = 0.f, S1 = 0.f;
            #pragma unroll 4
            for (int i = 0; i < 16; ++i) {
                float4 n4 = np4[i];
                float p;
                p = __builtin_amdgcn_exp2f(A*n4.x); S0 += p; S1 = fmaf(p, n4.x, S1);
                p = __builtin_amdgcn_exp2f(A*n4.y); S0 += p; S1 = fmaf(p, n4.y, S1);
                p = __builtin_amdgcn_exp2f(A*n4.z); S0 += p; S1 = fmaf(p, n4.z, S1);
                p = __builtin_amdgcn_exp2f(A*n4.w); S0 += p; S1 = fmaf(p, n4.w, S1);
            }
            S0 = qsum(S0); S1 = qsum(S1);
            if (kq == 0) tab[0][jj] = S1 * __builtin_amdgcn_rcpf(S0);
        } else {
            const float C0 = c0a * xnode + c0b;
            const float C1 = c1a * xnode + c1b;
            const float4* mp4 = (const float4*)mca[kq];
            float T0 = 0.f, T1 = 0.f, T2 = 0.f;
            #pragma unroll 4
            for (int i = 0; i < 32; ++i) {
                float4 m4 = mp4[i];
                float p;
                p = __builtin_amdgcn_exp2f(C0*m4.x + C1*m4.y);
                T0 += p; T1 = fmaf(p, m4.x, T1); T2 = fmaf(p, m4.y, T2);
                p = __builtin_amdgcn_exp2f(C0*m4.z + C1*m4.w);
                T0 += p; T1 = fmaf(p, m4.z, T1); T2 = fmaf(p, m4.w, T2);
            }
            T0 = qsum(T0); T1 = qsum(T1); T2 = qsum(T2);
            if (kq == 0) {
                float r = __builtin_amdgcn_rcpf(T0);
                tab[1][jj] = T1 * r;
                tab[2][jj] = T2 * r;
            }
        }
    }
    __syncthreads();   // tables ready

    // ---- DCT-II -> Chebyshev coefficients (96 threads; rotation recurrence)
    if (tid < 96) {
        const int s = tid >> 5, i = tid & 31;
        const float th = (float)i * (PI_F / 64.f);
        float cc = cosf(th), ss = sinf(th);
        const float rc = cc*cc - ss*ss;      // cos(2*i*th0)
        const float rs = 2.f * cc * ss;      // sin(2*i*th0)
        const float* tb = tab[s];
        float acc = tb[0] * cc;
        #pragma unroll 8
        for (int j = 1; j < 32; ++j) {
            float nc = cc*rc - ss*rs;
            ss = ss*rc + cc*rs;
            cc = nc;
            acc = fmaf(tb[j], cc, acc);
        }
        ctab[s][i] = acc * ((i == 0) ? (1.f/32.f) : (2.f/32.f));
    }
    __syncthreads();   // coefficients ready

    // ---- query phase: exact algebra + 3 Clenshaw evals, zero exps ----
    // SA
    float R  = clenshaw32(ctab[0], nq);
    float h0 = fmaf(nq, g0, b0);
    float h1 = fmaf(-nq, g1, b1);
    {
        float a0 = fmaf(av0, R, bv0);
        float a1 = fmaf(av1, R, bv1);
        h0 += a0*sa_w_out[0] + a1*sa_w_out[1] + sa_b_out[0];
        h1 += a0*sa_w_out[2] + a1*sa_w_out[3] + sa_b_out[1];
    }
    // LN2 (exact; the sharp map lives here, not in the interpolant)
    float d2 = 0.5f * (h0 - h1);
    float n2 = d2 * rsqrtf(d2*d2 + LN_EPS);
    h0 = fmaf(n2, G0, B0);
    h1 = fmaf(-n2, G1, B1);
    // CA
    {
        float U1 = clenshaw32(ctab[1], n2);
        float U2 = clenshaw32(ctab[2], n2);
        float A0 = ca_w_in[8]*U1  + ca_w_in[9]*U2  + ca_b_in[4];
        float A1 = ca_w_in[10]*U1 + ca_w_in[11]*U2 + ca_b_in[5];
        h0 += A0*ca_w_out[0] + A1*ca_w_out[1] + ca_b_out[0];
        h1 += A0*ca_w_out[2] + A1*ca_w_out[3] + ca_b_out[1];
    }
    // LN3
    {
        float d = 0.5f * (h0 - h1);
        float n = d * rsqrtf(d*d + LN_EPS);
        h0 =  n*ln3_g[0] + ln3_b[0];
        h1 = -n*ln3_g[1] + ln3_b[1];
    }
    // FFN: Linear(2,10) -> LN(10) -> ReLU -> Linear(10,2), residual
    {
        float ff[10];
        #pragma unroll
        for (int i = 0; i < 10; ++i)
            ff[i] = h0*f_w1[2*i] + h1*f_w1[2*i+1] + f_b1[i];
        float mu = 0.f;
        #pragma unroll
        for (int i = 0; i < 10; ++i) mu += ff[i];
        mu *= 0.1f;
        float var = 0.f;
        #pragma unroll
        for (int i = 0; i < 10; ++i) { float d = ff[i] - mu; var += d * d; }
        var *= 0.1f;
        float r = rsqrtf(var + LN_EPS);
        float o0 = 0.f, o1 = 0.f;
        #pragma unroll
        for (int i = 0; i < 10; ++i) {
            float n = (ff[i] - mu) * r * f_ln_g[i] + f_ln_b[i];
            n = fmaxf(n, 0.f);
            o0 += n * f_w2[i];               // f_w2 is [2,10] row-major
            o1 += n * f_w2[10 + i];
        }
        h0 += o0 + f_b2[0];
        h1 += o1 + f_b2[1];
    }

    ((float2*)out)[row * NTOK + tid] = make_float2(h0, h1);
}

extern "C" void kernel_launch(void* const* d_in, const int* in_sizes, int n_in,
                              void* d_out, int out_size, void* d_ws, size_t ws_size,
                              hipStream_t stream) {
    const float* x        = (const float*)d_in[0];
    const float* m        = (const float*)d_in[1];
    const float* sa_w_in  = (const float*)d_in[2];
    const float* sa_b_in  = (const float*)d_in[3];
    const float* sa_w_out = (const float*)d_in[4];
    const float* sa_b_out = (const float*)d_in[5];
    const float* ca_w_in  = (const float*)d_in[6];
    const float* ca_b_in  = (const float*)d_in[7];
    const float* ca_w_out = (const float*)d_in[8];
    const float* ca_b_out = (const float*)d_in[9];
    const float* ln1_g    = (const float*)d_in[10];
    const float* ln1_b    = (const float*)d_in[11];
    const float* ln2_g    = (const float*)d_in[12];
    const float* ln2_b    = (const float*)d_in[13];
    const float* ln3_g    = (const float*)d_in[14];
    const float* ln3_b    = (const float*)d_in[15];
    const float* f_w1     = (const float*)d_in[16];
    const float* f_b1     = (const float*)d_in[17];
    const float* f_ln_g   = (const float*)d_in[18];
    const float* f_ln_b   = (const float*)d_in[19];
    const float* f_w2     = (const float*)d_in[20];
    const float* f_b2     = (const float*)d_in[21];

    const int nbatch = in_sizes[0] / (NTOK * 2);   // 1024
    att_decoder_kernel<<<nbatch, NTOK, 0, stream>>>(
        x, m, sa_w_in, sa_b_in, sa_w_out, sa_b_out,
        ca_w_in, ca_b_in, ca_w_out, ca_b_out,
        ln1_g, ln1_b, ln2_g, ln2_b, ln3_g, ln3_b,
        f_w1, f_b1, f_ln_g, f_ln_b, f_w2, f_b2,
        (float*)d_out);
}

// Round 12
// 103.840 us; speedup vs baseline: 1.1713x; 1.0519x over previous
//
#include <hip/hip_runtime.h>
#include <math.h>

#define NTOK 256
#define LOG2E 1.44269504088896340736f
#define LN_EPS 1e-5f

// quad-perm DPP (VALU pipe): xor1 = 0xB1, xor2 = 0x4E
template <int CTRL>
static __device__ __forceinline__ float dppq(float v) {
    return __int_as_float(
        __builtin_amdgcn_update_dpp(0, __float_as_int(v), CTRL, 0xF, 0xF, true));
}
// ds_swizzle BitMode xor4 (offset 0x101F)
static __device__ __forceinline__ float swz_xor4(float v) {
    return __int_as_float(__builtin_amdgcn_ds_swizzle(__float_as_int(v), 0x101F));
}
static __device__ __forceinline__ float osum(float v) {   // 8-lane group sum
    v += dppq<0xB1>(v);
    v += dppq<0x4E>(v);
    v += swz_xor4(v);
    return v;
}

// Clenshaw for 16 Chebyshev coefficients (c[0] + sum c[i] T_i(x)), b128 packs.
static __device__ __forceinline__ float clenshaw16(const float* c, float x) {
    const float4* c4 = (const float4*)c;
    float x2 = x + x;
    float b1 = 0.f, b2 = 0.f, b;
#define STEPC(cv) b = fmaf(x2, b1, cv) - b2; b2 = b1; b1 = b;
    float4 q;
    q = c4[3]; STEPC(q.w) STEPC(q.z) STEPC(q.y) STEPC(q.x)
    q = c4[2]; STEPC(q.w) STEPC(q.z) STEPC(q.y) STEPC(q.x)
    q = c4[1]; STEPC(q.w) STEPC(q.z) STEPC(q.y) STEPC(q.x)
    q = c4[0]; STEPC(q.w) STEPC(q.z) STEPC(q.y)
#undef STEPC
    return fmaf(x, b1, q.x) - b2;
}

// R11 structure (verified absmax ~0 at P=32) with P=16:
// per row, 16-node Chebyshev tables of R(nq), U1(n2), U2(n2); 32 node-jobs
// x 8-way split-k (all 256 threads); DCT-16 via rotation recurrence with raw
// v_cos/v_sin; query phase = exact algebra + 3 Clenshaw-16 evals, zero exps.
__global__ __launch_bounds__(256, 4)
void att_decoder_kernel(
    const float* __restrict__ x, const float* __restrict__ m,
    const float* __restrict__ sa_w_in, const float* __restrict__ sa_b_in,
    const float* __restrict__ sa_w_out, const float* __restrict__ sa_b_out,
    const float* __restrict__ ca_w_in, const float* __restrict__ ca_b_in,
    const float* __restrict__ ca_w_out, const float* __restrict__ ca_b_out,
    const float* __restrict__ ln1_g, const float* __restrict__ ln1_b,
    const float* __restrict__ ln2_g, const float* __restrict__ ln2_b,
    const float* __restrict__ ln3_g, const float* __restrict__ ln3_b,
    const float* __restrict__ f_w1, const float* __restrict__ f_b1,
    const float* __restrict__ f_ln_g, const float* __restrict__ f_ln_b,
    const float* __restrict__ f_w2, const float* __restrict__ f_b2,
    float* __restrict__ out)
{
    const int tid = threadIdx.x;
    const int row = blockIdx.x;

    __shared__ alignas(16) float  n_sa[8][40];   // LN1 scalar, 8 key-octants
    __shared__ alignas(16) float2 mca [8][44];   // raw m, 8 key-octants
    __shared__ float tab[3][16];                 // R / U1 / U2 node values
    __shared__ alignas(16) float ctab[3][16];    // Chebyshev coefficients

    // ---- stage keys + own-query LN1 scalar ----
    float2 xv = ((const float2*)x)[row * NTOK + tid];
    float dq = 0.5f * (xv.x - xv.y);
    float nq = dq * rsqrtf(dq * dq + LN_EPS);
    n_sa[tid >> 5][tid & 31] = nq;
    mca [tid >> 5][tid & 31] = ((const float2*)m)[row * NTOK + tid];

    // ---- block-uniform linearization constants ----
    const float g0 = ln1_g[0], b0 = ln1_b[0], g1 = ln1_g[1], b1 = ln1_b[1];
    const float scl = 0.7071067811865476f * LOG2E;
    const float ak0 = g0*sa_w_in[4]  - g1*sa_w_in[5];
    const float ak1 = g0*sa_w_in[6]  - g1*sa_w_in[7];
    const float av0 = g0*sa_w_in[8]  - g1*sa_w_in[9];
    const float bv0 = b0*sa_w_in[8]  + b1*sa_w_in[9]  + sa_b_in[4];
    const float av1 = g0*sa_w_in[10] - g1*sa_w_in[11];
    const float bv1 = b0*sa_w_in[10] + b1*sa_w_in[11] + sa_b_in[5];
    const float kq0 = sa_w_in[0]*g0 - sa_w_in[1]*g1;
    const float kb0 = sa_w_in[0]*b0 + sa_w_in[1]*b1 + sa_b_in[0];
    const float kq1 = sa_w_in[2]*g0 - sa_w_in[3]*g1;
    const float kb1 = sa_w_in[2]*b0 + sa_w_in[3]*b1 + sa_b_in[1];
    const float Asc  = scl * (kq0*ak0 + kq1*ak1);
    const float Aoff = scl * (kb0*ak0 + kb1*ak1);
    const float G0 = ln2_g[0], B0 = ln2_b[0], G1 = ln2_g[1], B1 = ln2_b[1];
    const float e0a = ca_w_in[0]*G0 - ca_w_in[1]*G1;
    const float e0b = ca_w_in[0]*B0 + ca_w_in[1]*B1 + ca_b_in[0];
    const float e1a = ca_w_in[2]*G0 - ca_w_in[3]*G1;
    const float e1b = ca_w_in[2]*B0 + ca_w_in[3]*B1 + ca_b_in[1];
    const float c0a = scl * (e0a*ca_w_in[4] + e1a*ca_w_in[6]);
    const float c0b = scl * (e0b*ca_w_in[4] + e1b*ca_w_in[6]);
    const float c1a = scl * (e0a*ca_w_in[5] + e1a*ca_w_in[7]);
    const float c1b = scl * (e0b*ca_w_in[5] + e1b*ca_w_in[7]);

    __syncthreads();   // keys staged

    // ---- table phase: 32 node-jobs (16 SA + 16 CA) x 8-way split-k ----
    {
        const int job = tid >> 3, ko = tid & 7;
        const int jj = job & 15;
        // x_j = cos((2j+1)*pi/32) ; v_cos takes revolutions: (2j+1)/64
        const float xnode =
            __builtin_amdgcn_cosf((float)(2*jj + 1) * (1.f/64.f));
        if (job < 16) {
            const float A = Asc * xnode + Aoff;
            const float4* np4 = (const float4*)n_sa[ko];
            float S0 = 0.f, S1 = 0.f;
            #pragma unroll
            for (int i = 0; i < 8; ++i) {
                float4 n4 = np4[i];
                float p;
                p = __builtin_amdgcn_exp2f(A*n4.x); S0 += p; S1 = fmaf(p, n4.x, S1);
                p = __builtin_amdgcn_exp2f(A*n4.y); S0 += p; S1 = fmaf(p, n4.y, S1);
                p = __builtin_amdgcn_exp2f(A*n4.z); S0 += p; S1 = fmaf(p, n4.z, S1);
                p = __builtin_amdgcn_exp2f(A*n4.w); S0 += p; S1 = fmaf(p, n4.w, S1);
            }
            S0 = osum(S0); S1 = osum(S1);
            if (ko == 0) tab[0][jj] = S1 * __builtin_amdgcn_rcpf(S0);
        } else {
            const float C0 = c0a * xnode + c0b;
            const float C1 = c1a * xnode + c1b;
            const float4* mp4 = (const float4*)mca[ko];
            float T0 = 0.f, T1 = 0.f, T2 = 0.f;
            #pragma unroll
            for (int i = 0; i < 16; ++i) {
                float4 m4 = mp4[i];
                float p;
                p = __builtin_amdgcn_exp2f(C0*m4.x + C1*m4.y);
                T0 += p; T1 = fmaf(p, m4.x, T1); T2 = fmaf(p, m4.y, T2);
                p = __builtin_amdgcn_exp2f(C0*m4.z + C1*m4.w);
                T0 += p; T1 = fmaf(p, m4.z, T1); T2 = fmaf(p, m4.w, T2);
            }
            T0 = osum(T0); T1 = osum(T1); T2 = osum(T2);
            if (ko == 0) {
                float r = __builtin_amdgcn_rcpf(T0);
                tab[1][jj] = T1 * r;
                tab[2][jj] = T2 * r;
            }
        }
    }
    __syncthreads();   // tables ready

    // ---- DCT-II (P=16) -> Chebyshev coefficients, 48 threads ----
    if (tid < 48) {
        const int s = tid >> 4, i = tid & 15;
        // angles: start i*pi/32 (rev i/64), step i*pi/16 (rev i/32)
        float cc = __builtin_amdgcn_cosf((float)i * (1.f/64.f));
        float ss = __builtin_amdgcn_sinf((float)i * (1.f/64.f));
        const float rc = __builtin_amdgcn_cosf((float)i * (1.f/32.f));
        const float rs = __builtin_amdgcn_sinf((float)i * (1.f/32.f));
        const float* tb = tab[s];
        float acc = tb[0] * cc;
        #pragma unroll
        for (int j = 1; j < 16; ++j) {
            float nc = cc*rc - ss*rs;
            ss = ss*rc + cc*rs;
            cc = nc;
            acc = fmaf(tb[j], cc, acc);
        }
        ctab[s][i] = acc * ((i == 0) ? (1.f/16.f) : (2.f/16.f));
    }
    __syncthreads();   // coefficients ready

    // ---- query phase: exact algebra + 3 Clenshaw-16 evals, zero exps ----
    float R  = clenshaw16(ctab[0], nq);
    float h0 = fmaf(nq, g0, b0);
    float h1 = fmaf(-nq, g1, b1);
    {
        float a0 = fmaf(av0, R, bv0);
        float a1 = fmaf(av1, R, bv1);
        h0 += a0*sa_w_out[0] + a1*sa_w_out[1] + sa_b_out[0];
        h1 += a0*sa_w_out[2] + a1*sa_w_out[3] + sa_b_out[1];
    }
    // LN2 exact (sharp map must not enter the interpolant)
    float d2 = 0.5f * (h0 - h1);
    float n2 = d2 * rsqrtf(d2*d2 + LN_EPS);
    h0 = fmaf(n2, G0, B0);
    h1 = fmaf(-n2, G1, B1);
    {
        float U1 = clenshaw16(ctab[1], n2);
        float U2 = clenshaw16(ctab[2], n2);
        float A0 = ca_w_in[8]*U1  + ca_w_in[9]*U2  + ca_b_in[4];
        float A1 = ca_w_in[10]*U1 + ca_w_in[11]*U2 + ca_b_in[5];
        h0 += A0*ca_w_out[0] + A1*ca_w_out[1] + ca_b_out[0];
        h1 += A0*ca_w_out[2] + A1*ca_w_out[3] + ca_b_out[1];
    }
    // LN3
    {
        float d = 0.5f * (h0 - h1);
        float n = d * rsqrtf(d*d + LN_EPS);
        h0 =  n*ln3_g[0] + ln3_b[0];
        h1 = -n*ln3_g[1] + ln3_b[1];
    }
    // FFN: Linear(2,10) -> LN(10) -> ReLU -> Linear(10,2), residual
    {
        float ff[10];
        #pragma unroll
        for (int i = 0; i < 10; ++i)
            ff[i] = h0*f_w1[2*i] + h1*f_w1[2*i+1] + f_b1[i];
        float mu = 0.f;
        #pragma unroll
        for (int i = 0; i < 10; ++i) mu += ff[i];
        mu *= 0.1f;
        float var = 0.f;
        #pragma unroll
        for (int i = 0; i < 10; ++i) { float d = ff[i] - mu; var += d * d; }
        var *= 0.1f;
        float r = rsqrtf(var + LN_EPS);
        float o0 = 0.f, o1 = 0.f;
        #pragma unroll
        for (int i = 0; i < 10; ++i) {
            float n = (ff[i] - mu) * r * f_ln_g[i] + f_ln_b[i];
            n = fmaxf(n, 0.f);
            o0 += n * f_w2[i];               // f_w2 is [2,10] row-major
            o1 += n * f_w2[10 + i];
        }
        h0 += o0 + f_b2[0];
        h1 += o1 + f_b2[1];
    }

    ((float2*)out)[row * NTOK + tid] = make_float2(h0, h1);
}

extern "C" void kernel_launch(void* const* d_in, const int* in_sizes, int n_in,
                              void* d_out, int out_size, void* d_ws, size_t ws_size,
                              hipStream_t stream) {
    const float* x        = (const float*)d_in[0];
    const float* m        = (const float*)d_in[1];
    const float* sa_w_in  = (const float*)d_in[2];
    const float* sa_b_in  = (const float*)d_in[3];
    const float* sa_w_out = (const float*)d_in[4];
    const float* sa_b_out = (const float*)d_in[5];
    const float* ca_w_in  = (const float*)d_in[6];
    const float* ca_b_in  = (const float*)d_in[7];
    const float* ca_w_out = (const float*)d_in[8];
    const float* ca_b_out = (const float*)d_in[9];
    const float* ln1_g    = (const float*)d_in[10];
    const float* ln1_b    = (const float*)d_in[11];
    const float* ln2_g    = (const float*)d_in[12];
    const float* ln2_b    = (const float*)d_in[13];
    const float* ln3_g    = (const float*)d_in[14];
    const float* ln3_b    = (const float*)d_in[15];
    const float* f_w1     = (const float*)d_in[16];
    const float* f_b1     = (const float*)d_in[17];
    const float* f_ln_g   = (const float*)d_in[18];
    const float* f_ln_b   = (const float*)d_in[19];
    const float* f_w2     = (const float*)d_in[20];
    const float* f_b2     = (const float*)d_in[21];

    const int nbatch = in_sizes[0] / (NTOK * 2);   // 1024
    att_decoder_kernel<<<nbatch, NTOK, 0, stream>>>(
        x, m, sa_w_in, sa_b_in, sa_w_out, sa_b_out,
        ca_w_in, ca_b_in, ca_w_out, ca_b_out,
        ln1_g, ln1_b, ln2_g, ln2_b, ln3_g, ln3_b,
        f_w1, f_b1, f_ln_g, f_ln_b, f_w2, f_b2,
        (float*)d_out);
}

// Round 14
// 101.190 us; speedup vs baseline: 1.2020x; 1.0262x over previous
//
#include <hip/hip_runtime.h>
#include <math.h>

#define NTOK 256
#define LOG2E 1.44269504088896340736f
#define LN_EPS 1e-5f

// quad-perm DPP (VALU pipe): xor1 = 0xB1, xor2 = 0x4E
template <int CTRL>
static __device__ __forceinline__ float dppq(float v) {
    return __int_as_float(
        __builtin_amdgcn_update_dpp(0, __float_as_int(v), CTRL, 0xF, 0xF, true));
}
// ds_swizzle BitMode: xor4 = 0x101F, xor8 = 0x201F
static __device__ __forceinline__ float swz_xor4(float v) {
    return __int_as_float(__builtin_amdgcn_ds_swizzle(__float_as_int(v), 0x101F));
}
static __device__ __forceinline__ float swz_xor8(float v) {
    return __int_as_float(__builtin_amdgcn_ds_swizzle(__float_as_int(v), 0x201F));
}
static __device__ __forceinline__ float sum16(float v) {  // 16-lane group sum
    v += dppq<0xB1>(v);
    v += dppq<0x4E>(v);
    v += swz_xor4(v);
    v += swz_xor8(v);
    return v;
}

// Clenshaw for 8 Chebyshev coefficients (c[0] + sum c[i] T_i(x)).
static __device__ __forceinline__ float clenshaw8(const float* c, float x) {
    const float4* c4 = (const float4*)c;
    float x2 = x + x;
    float b1 = 0.f, b2 = 0.f, b;
#define STEPC(cv) b = fmaf(x2, b1, cv) - b2; b2 = b1; b1 = b;
    float4 q;
    q = c4[1]; STEPC(q.w) STEPC(q.z) STEPC(q.y) STEPC(q.x)
    q = c4[0]; STEPC(q.w) STEPC(q.z) STEPC(q.y)
#undef STEPC
    return fmaf(x, b1, q.x) - b2;
}

// R11/R12 structure at P=8 (P=16 gave absmax ~0 -> rho >~ 2.7 -> P=8 error
// ~3e-4, 100x under threshold). 16 node-jobs (8 SA + 8 CA) x 16-way split-k:
// all 256 threads active, 16 exps each. DCT-8 rotation recurrence with raw
// v_cos/v_sin; query = exact algebra + 3 Clenshaw-8 evals, zero exps.
__global__ __launch_bounds__(256, 4)
void att_decoder_kernel(
    const float* __restrict__ x, const float* __restrict__ m,
    const float* __restrict__ sa_w_in, const float* __restrict__ sa_b_in,
    const float* __restrict__ sa_w_out, const float* __restrict__ sa_b_out,
    const float* __restrict__ ca_w_in, const float* __restrict__ ca_b_in,
    const float* __restrict__ ca_w_out, const float* __restrict__ ca_b_out,
    const float* __restrict__ ln1_g, const float* __restrict__ ln1_b,
    const float* __restrict__ ln2_g, const float* __restrict__ ln2_b,
    const float* __restrict__ ln3_g, const float* __restrict__ ln3_b,
    const float* __restrict__ f_w1, const float* __restrict__ f_b1,
    const float* __restrict__ f_ln_g, const float* __restrict__ f_ln_b,
    const float* __restrict__ f_w2, const float* __restrict__ f_b2,
    float* __restrict__ out)
{
    const int tid = threadIdx.x;
    const int row = blockIdx.x;

    __shared__ alignas(16) float  n_sa[16][20];  // LN1 scalar, 16 partitions
    __shared__ alignas(16) float2 mca [16][18];  // raw m, 16 partitions
    __shared__ float tab[3][8];                  // R / U1 / U2 node values
    __shared__ alignas(16) float ctab[3][8];     // Chebyshev coefficients

    // ---- stage keys + own-query LN1 scalar ----
    float2 xv = ((const float2*)x)[row * NTOK + tid];
    float dq = 0.5f * (xv.x - xv.y);
    float nq = dq * rsqrtf(dq * dq + LN_EPS);
    n_sa[tid >> 4][tid & 15] = nq;
    mca [tid >> 4][tid & 15] = ((const float2*)m)[row * NTOK + tid];

    // ---- block-uniform linearization constants ----
    const float g0 = ln1_g[0], b0 = ln1_b[0], g1 = ln1_g[1], b1 = ln1_b[1];
    const float scl = 0.7071067811865476f * LOG2E;
    const float ak0 = g0*sa_w_in[4]  - g1*sa_w_in[5];
    const float ak1 = g0*sa_w_in[6]  - g1*sa_w_in[7];
    const float av0 = g0*sa_w_in[8]  - g1*sa_w_in[9];
    const float bv0 = b0*sa_w_in[8]  + b1*sa_w_in[9]  + sa_b_in[4];
    const float av1 = g0*sa_w_in[10] - g1*sa_w_in[11];
    const float bv1 = b0*sa_w_in[10] + b1*sa_w_in[11] + sa_b_in[5];
    const float kq0 = sa_w_in[0]*g0 - sa_w_in[1]*g1;
    const float kb0 = sa_w_in[0]*b0 + sa_w_in[1]*b1 + sa_b_in[0];
    const float kq1 = sa_w_in[2]*g0 - sa_w_in[3]*g1;
    const float kb1 = sa_w_in[2]*b0 + sa_w_in[3]*b1 + sa_b_in[1];
    const float Asc  = scl * (kq0*ak0 + kq1*ak1);
    const float Aoff = scl * (kb0*ak0 + kb1*ak1);
    const float G0 = ln2_g[0], B0 = ln2_b[0], G1 = ln2_g[1], B1 = ln2_b[1];
    const float e0a = ca_w_in[0]*G0 - ca_w_in[1]*G1;
    const float e0b = ca_w_in[0]*B0 + ca_w_in[1]*B1 + ca_b_in[0];
    const float e1a = ca_w_in[2]*G0 - ca_w_in[3]*G1;
    const float e1b = ca_w_in[2]*B0 + ca_w_in[3]*B1 + ca_b_in[1];
    const float c0a = scl * (e0a*ca_w_in[4] + e1a*ca_w_in[6]);
    const float c0b = scl * (e0b*ca_w_in[4] + e1b*ca_w_in[6]);
    const float c1a = scl * (e0a*ca_w_in[5] + e1a*ca_w_in[7]);
    const float c1b = scl * (e0b*ca_w_in[5] + e1b*ca_w_in[7]);

    __syncthreads();   // keys staged

    // ---- table phase: 16 node-jobs x 16-way split-k (16 keys each) ----
    {
        const int job = tid >> 4, ks = tid & 15;   // job wave-subgroup-uniform
        const int jj = job & 7;
        // x_j = cos((2j+1)*pi/16); v_cos takes revolutions: (2j+1)/32
        const float xnode =
            __builtin_amdgcn_cosf((float)(2*jj + 1) * (1.f/32.f));
        if (job < 8) {
            const float A = Asc * xnode + Aoff;
            const float4* np4 = (const float4*)n_sa[ks];
            float S0 = 0.f, S1 = 0.f;
            #pragma unroll
            for (int i = 0; i < 4; ++i) {
                float4 n4 = np4[i];
                float p;
                p = __builtin_amdgcn_exp2f(A*n4.x); S0 += p; S1 = fmaf(p, n4.x, S1);
                p = __builtin_amdgcn_exp2f(A*n4.y); S0 += p; S1 = fmaf(p, n4.y, S1);
                p = __builtin_amdgcn_exp2f(A*n4.z); S0 += p; S1 = fmaf(p, n4.z, S1);
                p = __builtin_amdgcn_exp2f(A*n4.w); S0 += p; S1 = fmaf(p, n4.w, S1);
            }
            S0 = sum16(S0); S1 = sum16(S1);
            if (ks == 0) tab[0][jj] = S1 * __builtin_amdgcn_rcpf(S0);
        } else {
            const float C0 = c0a * xnode + c0b;
            const float C1 = c1a * xnode + c1b;
            const float4* mp4 = (const float4*)mca[ks];
            float T0 = 0.f, T1 = 0.f, T2 = 0.f;
            #pragma unroll
            for (int i = 0; i < 8; ++i) {
                float4 m4 = mp4[i];
                float p;
                p = __builtin_amdgcn_exp2f(C0*m4.x + C1*m4.y);
                T0 += p; T1 = fmaf(p, m4.x, T1); T2 = fmaf(p, m4.y, T2);
                p = __builtin_amdgcn_exp2f(C0*m4.z + C1*m4.w);
                T0 += p; T1 = fmaf(p, m4.z, T1); T2 = fmaf(p, m4.w, T2);
            }
            T0 = sum16(T0); T1 = sum16(T1); T2 = sum16(T2);
            if (ks == 0) {
                float r = __builtin_amdgcn_rcpf(T0);
                tab[1][jj] = T1 * r;
                tab[2][jj] = T2 * r;
            }
        }
    }
    __syncthreads();   // tables ready

    // ---- DCT-II (P=8) -> Chebyshev coefficients, 24 threads ----
    if (tid < 24) {
        const int s = tid >> 3, i = tid & 7;
        // angles: start i*pi/16 (rev i/32), step i*pi/8 (rev i/16)
        float cc = __builtin_amdgcn_cosf((float)i * (1.f/32.f));
        float ss = __builtin_amdgcn_sinf((float)i * (1.f/32.f));
        const float rc = __builtin_amdgcn_cosf((float)i * (1.f/16.f));
        const float rs = __builtin_amdgcn_sinf((float)i * (1.f/16.f));
        const float* tb = tab[s];
        float acc = tb[0] * cc;
        #pragma unroll
        for (int j = 1; j < 8; ++j) {
            float nc = cc*rc - ss*rs;
            ss = ss*rc + cc*rs;
            cc = nc;
            acc = fmaf(tb[j], cc, acc);
        }
        ctab[s][i] = acc * ((i == 0) ? (1.f/8.f) : (2.f/8.f));
    }
    __syncthreads();   // coefficients ready

    // ---- query phase: exact algebra + 3 Clenshaw-8 evals, zero exps ----
    float R  = clenshaw8(ctab[0], nq);
    float h0 = fmaf(nq, g0, b0);
    float h1 = fmaf(-nq, g1, b1);
    {
        float a0 = fmaf(av0, R, bv0);
        float a1 = fmaf(av1, R, bv1);
        h0 += a0*sa_w_out[0] + a1*sa_w_out[1] + sa_b_out[0];
        h1 += a0*sa_w_out[2] + a1*sa_w_out[3] + sa_b_out[1];
    }
    // LN2 exact (sharp map stays out of the interpolant)
    float d2 = 0.5f * (h0 - h1);
    float n2 = d2 * rsqrtf(d2*d2 + LN_EPS);
    h0 = fmaf(n2, G0, B0);
    h1 = fmaf(-n2, G1, B1);
    {
        float U1 = clenshaw8(ctab[1], n2);
        float U2 = clenshaw8(ctab[2], n2);
        float A0 = ca_w_in[8]*U1  + ca_w_in[9]*U2  + ca_b_in[4];
        float A1 = ca_w_in[10]*U1 + ca_w_in[11]*U2 + ca_b_in[5];
        h0 += A0*ca_w_out[0] + A1*ca_w_out[1] + ca_b_out[0];
        h1 += A0*ca_w_out[2] + A1*ca_w_out[3] + ca_b_out[1];
    }
    // LN3
    {
        float d = 0.5f * (h0 - h1);
        float n = d * rsqrtf(d*d + LN_EPS);
        h0 =  n*ln3_g[0] + ln3_b[0];
        h1 = -n*ln3_g[1] + ln3_b[1];
    }
    // FFN: Linear(2,10) -> LN(10) -> ReLU -> Linear(10,2), residual
    {
        float ff[10];
        #pragma unroll
        for (int i = 0; i < 10; ++i)
            ff[i] = h0*f_w1[2*i] + h1*f_w1[2*i+1] + f_b1[i];
        float mu = 0.f;
        #pragma unroll
        for (int i = 0; i < 10; ++i) mu += ff[i];
        mu *= 0.1f;
        float var = 0.f;
        #pragma unroll
        for (int i = 0; i < 10; ++i) { float d = ff[i] - mu; var += d * d; }
        var *= 0.1f;
        float r = rsqrtf(var + LN_EPS);
        float o0 = 0.f, o1 = 0.f;
        #pragma unroll
        for (int i = 0; i < 10; ++i) {
            float n = (ff[i] - mu) * r * f_ln_g[i] + f_ln_b[i];
            n = fmaxf(n, 0.f);
            o0 += n * f_w2[i];               // f_w2 is [2,10] row-major
            o1 += n * f_w2[10 + i];
        }
        h0 += o0 + f_b2[0];
        h1 += o1 + f_b2[1];
    }

    ((float2*)out)[row * NTOK + tid] = make_float2(h0, h1);
}

extern "C" void kernel_launch(void* const* d_in, const int* in_sizes, int n_in,
                              void* d_out, int out_size, void* d_ws, size_t ws_size,
                              hipStream_t stream) {
    const float* x        = (const float*)d_in[0];
    const float* m        = (const float*)d_in[1];
    const float* sa_w_in  = (const float*)d_in[2];
    const float* sa_b_in  = (const float*)d_in[3];
    const float* sa_w_out = (const float*)d_in[4];
    const float* sa_b_out = (const float*)d_in[5];
    const float* ca_w_in  = (const float*)d_in[6];
    const float* ca_b_in  = (const float*)d_in[7];
    const float* ca_w_out = (const float*)d_in[8];
    const float* ca_b_out = (const float*)d_in[9];
    const float* ln1_g    = (const float*)d_in[10];
    const float* ln1_b    = (const float*)d_in[11];
    const float* ln2_g    = (const float*)d_in[12];
    const float* ln2_b    = (const float*)d_in[13];
    const float* ln3_g    = (const float*)d_in[14];
    const float* ln3_b    = (const float*)d_in[15];
    const float* f_w1     = (const float*)d_in[16];
    const float* f_b1     = (const float*)d_in[17];
    const float* f_ln_g   = (const float*)d_in[18];
    const float* f_ln_b   = (const float*)d_in[19];
    const float* f_w2     = (const float*)d_in[20];
    const float* f_b2     = (const float*)d_in[21];

    const int nbatch = in_sizes[0] / (NTOK * 2);   // 1024
    att_decoder_kernel<<<nbatch, NTOK, 0, stream>>>(
        x, m, sa_w_in, sa_b_in, sa_w_out, sa_b_out,
        ca_w_in, ca_b_in, ca_w_out, ca_b_out,
        ln1_g, ln1_b, ln2_g, ln2_b, ln3_g, ln3_b,
        f_w1, f_b1, f_ln_g, f_ln_b, f_w2, f_b2,
        (float*)d_out);
}